// Round 19
// baseline (356.415 us; speedup 1.0000x reference)
//
#include <hip/hip_runtime.h>

// LightGCN: block-interleaved fused cvt+hist, XCD-class-partitioned fill,
// 8-nodes/wave bf16 gathers with cache-resident tables.
// E16 = bf16(emb); X1 = G(E16); X2 = G(X1); out = 0.25*(emb+X1+X2+G(X2)).

#define NNODES   500000
#define DIMV     64
#define NEDGE    1250000
#define NELEM    (NNODES * DIMV)          // 32,000,000
#define NELEM4   (NELEM / 4)

#define SCAN_BLK   256
#define SCAN_ITEMS 8
#define SCAN_CHUNK (SCAN_BLK * SCAN_ITEMS)              // 2048
#define NB1 ((NNODES + SCAN_CHUNK - 1) / SCAN_CHUNK)    // 245 (<= 256)

#define CVT_BLOCKS   (NELEM4 / 256)                     // 32768
#define EDGE2_BLOCKS ((NEDGE / 2 + 255) / 256)          // 2442
// interleaved fusion: 16-block groups = 14 cvt + 2 hist
#define FUSE_GROUPS  ((CVT_BLOCKS + 13) / 14)           // 2341
#define FUSE_BLOCKS  (FUSE_GROUPS * 16)                 // 37456

#define FILL_CLASSES  8
#define FILL_BPC      256                                // blocks per class
#define COLS_PER_CLS  (NNODES / FILL_CLASSES)            // 62500

typedef float  fx4 __attribute__((ext_vector_type(4)));

// bf16 helpers (RNE)
static __device__ __forceinline__ unsigned short f2bf(float f) {
    unsigned u = __float_as_uint(f);
    unsigned r = (u + 0x7fffu + ((u >> 16) & 1u)) >> 16;
    return (unsigned short)r;
}
static __device__ __forceinline__ float bflo(unsigned u) {
    return __uint_as_float(u << 16);
}
static __device__ __forceinline__ float bfhi(unsigned u) {
    return __uint_as_float(u & 0xffff0000u);
}

// ====== fused cvt+hist, block-interleaved (14:2 per 16-block group) ======
__global__ __launch_bounds__(256) void lgcn_cvt_hist(
    const float4* __restrict__ emb4, unsigned long long* __restrict__ dst,
    const int* __restrict__ col, int* __restrict__ cnt)
{
    const int grp = blockIdx.x >> 4;
    const int cls = blockIdx.x & 15;
    if (cls < 14) {
        int i = (grp * 14 + cls) * 256 + threadIdx.x;
        if (i >= NELEM4) return;
        float4 v = emb4[i];
        unsigned lo = (unsigned)f2bf(v.x) | ((unsigned)f2bf(v.y) << 16);
        unsigned hi = (unsigned)f2bf(v.z) | ((unsigned)f2bf(v.w) << 16);
        dst[i] = (unsigned long long)lo | ((unsigned long long)hi << 32); // cached
    } else {
        int t = (grp * 2 + (cls - 14)) * 256 + threadIdx.x;
        if (t >= NEDGE / 2) return;
        int2 c2 = reinterpret_cast<const int2*>(col)[t];
        if ((unsigned)c2.x < NNODES) atomicAdd(&cnt[c2.x], 1);
        if ((unsigned)c2.y < NNODES) atomicAdd(&cnt[c2.y], 1);
    }
}

// ======================= CSR scans =======================

__global__ __launch_bounds__(SCAN_BLK) void lgcn_scan1(
    const int* __restrict__ cnt, int* __restrict__ startv, int* __restrict__ bsum)
{
    __shared__ int sh[SCAN_BLK];
    int b = blockIdx.x;
    int base = b * SCAN_CHUNK;
    int tid = threadIdx.x;
    int v[SCAN_ITEMS];
    int local = 0;
    #pragma unroll
    for (int k = 0; k < SCAN_ITEMS; ++k) {
        int idx = base + tid * SCAN_ITEMS + k;
        v[k] = (idx < NNODES) ? cnt[idx] : 0;
        local += v[k];
    }
    sh[tid] = local;
    __syncthreads();
    for (int off = 1; off < SCAN_BLK; off <<= 1) {
        int x = (tid >= off) ? sh[tid - off] : 0;
        __syncthreads();
        sh[tid] += x;
        __syncthreads();
    }
    int run = (tid == 0) ? 0 : sh[tid - 1];
    if (tid == SCAN_BLK - 1) bsum[b] = sh[tid];
    #pragma unroll
    for (int k = 0; k < SCAN_ITEMS; ++k) {
        int idx = base + tid * SCAN_ITEMS + k;
        if (idx < NNODES) startv[idx] = run;
        run += v[k];
    }
}

__global__ __launch_bounds__(SCAN_BLK) void lgcn_scan2(int* __restrict__ bsum)
{
    __shared__ int sh[SCAN_BLK];
    int tid = threadIdx.x;
    sh[tid] = (tid < NB1) ? bsum[tid] : 0;
    __syncthreads();
    for (int off = 1; off < SCAN_BLK; off <<= 1) {
        int x = (tid >= off) ? sh[tid - off] : 0;
        __syncthreads();
        sh[tid] += x;
        __syncthreads();
    }
    if (tid < NB1) bsum[tid] = (tid == 0) ? 0 : sh[tid - 1];
}

__global__ __launch_bounds__(256) void lgcn_scan3(
    int* __restrict__ startv, int* __restrict__ cursor, const int* __restrict__ bsum)
{
    int i = blockIdx.x * blockDim.x + threadIdx.x;
    if (i < NNODES) {
        int s = startv[i] + bsum[i / SCAN_CHUNK];
        startv[i] = s;
        cursor[i] = s;
    }
    if (i == 0) startv[NNODES] = NEDGE;
}

// ============ fill: XCD-class col partition (blockIdx&7 == class) ============
__global__ __launch_bounds__(256) void lgcn_fill_part(
    const int* __restrict__ row, const int* __restrict__ col,
    const float* __restrict__ w, int* __restrict__ cursor,
    unsigned long long* __restrict__ pairs)
{
    const int cls = blockIdx.x & (FILL_CLASSES - 1);
    const int q   = blockIdx.x >> 3;
    const int lo  = cls * COLS_PER_CLS;
    const int hi  = lo + COLS_PER_CLS;
    const int2* col2 = reinterpret_cast<const int2*>(col);

    for (int t = q * 256 + threadIdx.x; t < NEDGE / 2; t += FILL_BPC * 256) {
        int2 c2 = col2[t];
        if (c2.x >= lo && c2.x < hi) {
            int e = 2 * t;
            int r = row[e]; float wt = w[e];
            if ((unsigned)r >= NNODES) { r = 0; wt = 0.f; }
            int p = atomicAdd(&cursor[c2.x], 1);
            pairs[p] = (unsigned long long)(unsigned)r
                     | ((unsigned long long)__float_as_uint(wt) << 32);
        }
        if (c2.y >= lo && c2.y < hi) {
            int e = 2 * t + 1;
            int r = row[e]; float wt = w[e];
            if ((unsigned)r >= NNODES) { r = 0; wt = 0.f; }
            int p = atomicAdd(&cursor[c2.y], 1);
            pairs[p] = (unsigned long long)(unsigned)r
                     | ((unsigned long long)__float_as_uint(wt) << 32);
        }
    }
}

// ======================= gather: 8 nodes/wave, 8 lanes/node =======================
// Unconditional clamped batch loads (r14-proven). Table writes CACHED so the
// next gather reads an L2/L3-hot table.
// MODE 0: E16 -> X1;  MODE 1: X1 -> X2;  MODE 2: X2+streams -> out fp32
template<int MODE>
__global__ __launch_bounds__(256, 4) void lgcn_gather(
    const unsigned short* __restrict__ src16, unsigned short* __restrict__ xout16,
    const float* __restrict__ emb, const unsigned short* __restrict__ x1,
    const unsigned short* __restrict__ x2, float* __restrict__ outp,
    const int2* __restrict__ pairs, const int* __restrict__ startv)
{
    int t = blockIdx.x * blockDim.x + threadIdx.x;
    int wid = t >> 6;               // wave id: 8 nodes/wave
    int lane = t & 63;
    int g = lane >> 3;              // node slot (0..7)
    int sub = lane & 7;             // dim octet (dims sub*8 .. sub*8+7)
    int n = wid * 8 + g;
    if (n >= NNODES) return;

    int s = startv[n];              // broadcast within 8-lane group
    int e = startv[n + 1];

    float a0=0.f,a1=0.f,a2=0.f,a3=0.f,a4=0.f,a5=0.f,a6=0.f,a7=0.f;

    for (int i = s; i < e; i += 8) {     // empty nodes skip entirely
        int2 pr[8];
        #pragma unroll
        for (int k = 0; k < 8; ++k) {
            int idx = i + k;
            idx = idx < e ? idx : e - 1;     // clamp; e>s here so e-1>=s
            pr[k] = pairs[idx];              // unconditional broadcast load
        }
        uint4 rv[8];
        #pragma unroll
        for (int k = 0; k < 8; ++k) {
            rv[k] = *reinterpret_cast<const uint4*>(
                &src16[(size_t)pr[k].x * DIMV + sub * 8]);   // unconditional
        }
        #pragma unroll
        for (int k = 0; k < 8; ++k) {
            float wk = (i + k < e) ? __int_as_float(pr[k].y) : 0.f;
            a0 = fmaf(wk, bflo(rv[k].x), a0);
            a1 = fmaf(wk, bfhi(rv[k].x), a1);
            a2 = fmaf(wk, bflo(rv[k].y), a2);
            a3 = fmaf(wk, bfhi(rv[k].y), a3);
            a4 = fmaf(wk, bflo(rv[k].z), a4);
            a5 = fmaf(wk, bfhi(rv[k].z), a5);
            a6 = fmaf(wk, bflo(rv[k].w), a6);
            a7 = fmaf(wk, bfhi(rv[k].w), a7);
        }
    }

    const size_t o = (size_t)n * DIMV + sub * 8;
    if (MODE == 2) {
        fx4 e0 = __builtin_nontemporal_load(reinterpret_cast<const fx4*>(&emb[o]));
        fx4 e1 = __builtin_nontemporal_load(reinterpret_cast<const fx4*>(&emb[o + 4]));
        uint4 u1 = *reinterpret_cast<const uint4*>(&x1[o]);      // cache-hot
        uint4 u2 = *reinterpret_cast<const uint4*>(&x2[o]);      // cache-hot
        fx4 r0, r1;
        r0.x = (e0.x + bflo(u1.x) + bflo(u2.x) + a0) * 0.25f;
        r0.y = (e0.y + bfhi(u1.x) + bfhi(u2.x) + a1) * 0.25f;
        r0.z = (e0.z + bflo(u1.y) + bflo(u2.y) + a2) * 0.25f;
        r0.w = (e0.w + bfhi(u1.y) + bfhi(u2.y) + a3) * 0.25f;
        r1.x = (e1.x + bflo(u1.z) + bflo(u2.z) + a4) * 0.25f;
        r1.y = (e1.y + bfhi(u1.z) + bfhi(u2.z) + a5) * 0.25f;
        r1.z = (e1.z + bflo(u1.w) + bflo(u2.w) + a6) * 0.25f;
        r1.w = (e1.w + bfhi(u1.w) + bfhi(u2.w) + a7) * 0.25f;
        __builtin_nontemporal_store(r0, reinterpret_cast<fx4*>(&outp[o]));
        __builtin_nontemporal_store(r1, reinterpret_cast<fx4*>(&outp[o + 4]));
    } else {
        unsigned long long lo =
              (unsigned long long)((unsigned)f2bf(a0) | ((unsigned)f2bf(a1) << 16))
            | ((unsigned long long)((unsigned)f2bf(a2) | ((unsigned)f2bf(a3) << 16)) << 32);
        unsigned long long hi =
              (unsigned long long)((unsigned)f2bf(a4) | ((unsigned)f2bf(a5) << 16))
            | ((unsigned long long)((unsigned)f2bf(a6) | ((unsigned)f2bf(a7) << 16)) << 32);
        // CACHED stores: this table is the next gather's random-read source
        reinterpret_cast<unsigned long long*>(&xout16[o])[0]    = lo;
        reinterpret_cast<unsigned long long*>(&xout16[o + 4])[0] = hi;
    }
}

// ======================= fallback: atomic scatter path (fp32) =======================

__global__ __launch_bounds__(256) void lgcn_init(
    const float4* __restrict__ emb, float4* __restrict__ acc,
    float4* __restrict__ A, float4* __restrict__ B)
{
    int i = blockIdx.x * blockDim.x + threadIdx.x;
    int stride = gridDim.x * blockDim.x;
    for (; i < NELEM4; i += stride) {
        float4 v = emb[i];
        acc[i] = v;
        A[i]   = v;
        B[i]   = make_float4(0.f, 0.f, 0.f, 0.f);
    }
}

__global__ __launch_bounds__(256) void lgcn_scatter(
    const float* __restrict__ xcur, float* __restrict__ xnext,
    const int* __restrict__ row, const int* __restrict__ col,
    const float* __restrict__ w)
{
    int t = blockIdx.x * blockDim.x + threadIdx.x;
    int e = t >> 4;
    if (e >= NEDGE) return;
    int d = (t & 15) << 2;
    int r = row[e];
    int c = col[e];
    if ((unsigned)r >= NNODES || (unsigned)c >= NNODES) return;
    float wt = w[e];
    const float4 v = *reinterpret_cast<const float4*>(xcur + (size_t)r * DIMV + d);
    float* dst = xnext + (size_t)c * DIMV + d;
    atomicAdd(dst + 0, wt * v.x);
    atomicAdd(dst + 1, wt * v.y);
    atomicAdd(dst + 2, wt * v.z);
    atomicAdd(dst + 3, wt * v.w);
}

__global__ __launch_bounds__(256) void lgcn_addzero(
    float4* __restrict__ acc, const float4* __restrict__ X, float4* __restrict__ Y)
{
    int i = blockIdx.x * blockDim.x + threadIdx.x;
    int stride = gridDim.x * blockDim.x;
    for (; i < NELEM4; i += stride) {
        float4 a = acc[i];
        float4 x = X[i];
        a.x += x.x; a.y += x.y; a.z += x.z; a.w += x.w;
        acc[i] = a;
        Y[i] = make_float4(0.f, 0.f, 0.f, 0.f);
    }
}

__global__ __launch_bounds__(256) void lgcn_final(
    float4* __restrict__ acc, const float4* __restrict__ X)
{
    int i = blockIdx.x * blockDim.x + threadIdx.x;
    int stride = gridDim.x * blockDim.x;
    for (; i < NELEM4; i += stride) {
        float4 a = acc[i];
        float4 x = X[i];
        a.x = (a.x + x.x) * 0.25f;
        a.y = (a.y + x.y) * 0.25f;
        a.z = (a.z + x.z) * 0.25f;
        a.w = (a.w + x.w) * 0.25f;
        acc[i] = a;
    }
}

// ======================= launch =======================

extern "C" void kernel_launch(void* const* d_in, const int* in_sizes, int n_in,
                              void* d_out, int out_size, void* d_ws, size_t ws_size,
                              hipStream_t stream) {
    const float* emb  = (const float*)d_in[0];   // [N, 64] fp32
    const int*   eidx = (const int*)d_in[1];     // [2, E] int32
    const float* ew   = (const float*)d_in[2];   // [E] fp32
    float* acc = (float*)d_out;                  // [N, 64]

    const int* row = eidx;
    const int* col = eidx + NEDGE;

    // workspace: E16, X1, X2 (bf16, 64 MB each) + CSR arrays
    unsigned short* E16 = (unsigned short*)d_ws;         // NELEM*2
    unsigned short* X1  = E16 + NELEM;                   // NELEM*2
    unsigned short* X2  = X1 + NELEM;                    // NELEM*2
    int2*  pairs  = (int2*)(X2 + NELEM);                 // 10e6 B (8-aligned)
    int*   startv = (int*)(pairs + NEDGE);               // (N+1)*4
    int*   cursor = startv + (NNODES + 1);               // N*4
    int*   bsum   = cursor + NNODES;                     // NB1*4
    const size_t needed = (size_t)3 * NELEM * 2 + (size_t)NEDGE * 8
                        + ((size_t)NNODES + 1) * 4 + (size_t)NNODES * 4 + (size_t)NB1 * 4;

    const int NODE_BLOCKS = (NNODES + 255) / 256;
    const int GW_BLOCKS   = (NNODES * 8 + 255) / 256;    // 8 nodes/wave

    if (ws_size >= needed) {
        // ---- fused bf16 table + CSR counts (block-interleaved) ----
        hipMemsetAsync(cursor, 0, (size_t)NNODES * 4, stream);
        lgcn_cvt_hist<<<FUSE_BLOCKS, 256, 0, stream>>>(
            (const float4*)emb, (unsigned long long*)E16, col, cursor);

        // ---- scans + partitioned fill ----
        lgcn_scan1<<<NB1, SCAN_BLK, 0, stream>>>(cursor, startv, bsum);
        lgcn_scan2<<<1, SCAN_BLK, 0, stream>>>(bsum);
        lgcn_scan3<<<NODE_BLOCKS, 256, 0, stream>>>(startv, cursor, bsum);
        lgcn_fill_part<<<FILL_CLASSES * FILL_BPC, 256, 0, stream>>>(
            row, col, ew, cursor, (unsigned long long*)pairs);

        // ---- layers ----
        lgcn_gather<0><<<GW_BLOCKS, 256, 0, stream>>>(
            E16, X1, nullptr, nullptr, nullptr, nullptr, pairs, startv);
        lgcn_gather<1><<<GW_BLOCKS, 256, 0, stream>>>(
            X1, X2, nullptr, nullptr, nullptr, nullptr, pairs, startv);
        lgcn_gather<2><<<GW_BLOCKS, 256, 0, stream>>>(
            X2, nullptr, emb, X1, X2, acc, pairs, startv);
    } else {
        // ---- fallback: proven fp32 atomic-scatter path ----
        float* A = (float*)d_ws;
        float* B = A + NELEM;
        const int SC_BLOCKS = (NEDGE * 16 + 255) / 256;
        lgcn_init<<<2048, 256, 0, stream>>>(
            (const float4*)emb, (float4*)acc, (float4*)A, (float4*)B);
        lgcn_scatter<<<SC_BLOCKS, 256, 0, stream>>>(A, B, row, col, ew);
        lgcn_addzero<<<2048, 256, 0, stream>>>((float4*)acc, (const float4*)B, (float4*)A);
        lgcn_scatter<<<SC_BLOCKS, 256, 0, stream>>>(B, A, row, col, ew);
        lgcn_addzero<<<2048, 256, 0, stream>>>((float4*)acc, (const float4*)A, (float4*)B);
        lgcn_scatter<<<SC_BLOCKS, 256, 0, stream>>>(A, B, row, col, ew);
        lgcn_final<<<2048, 256, 0, stream>>>((float4*)acc, (const float4*)B);
    }
}

// Round 20
// 320.480 us; speedup vs baseline: 1.1121x; 1.1121x over previous
//
#include <hip/hip_runtime.h>

// LightGCN: fused cvt+hist (sequential halves, wide cvt), XCD-class fill,
// 8-nodes/wave bf16 gathers with cache-resident tables.
// E16 = bf16(emb); X1 = G(E16); X2 = G(X1); out = 0.25*(emb+X1+X2+G(X2)).

#define NNODES   500000
#define DIMV     64
#define NEDGE    1250000
#define NELEM    (NNODES * DIMV)          // 32,000,000
#define NELEM4   (NELEM / 4)
#define NELEM8   (NELEM / 8)

#define SCAN_BLK   256
#define SCAN_ITEMS 8
#define SCAN_CHUNK (SCAN_BLK * SCAN_ITEMS)              // 2048
#define NB1 ((NNODES + SCAN_CHUNK - 1) / SCAN_CHUNK)    // 245 (<= 256)

#define CVT_BLOCKS   (NELEM8 / 256)                     // 15625 (2 float4/thread)
#define EDGE2_BLOCKS ((NEDGE / 2 + 255) / 256)          // 2442

#define FILL_CLASSES  8
#define FILL_BPC      256                                // blocks per class
#define COLS_PER_CLS  (NNODES / FILL_CLASSES)            // 62500

typedef float  fx4 __attribute__((ext_vector_type(4)));
typedef unsigned ui4 __attribute__((ext_vector_type(4)));

// bf16 helpers (RNE)
static __device__ __forceinline__ unsigned short f2bf(float f) {
    unsigned u = __float_as_uint(f);
    unsigned r = (u + 0x7fffu + ((u >> 16) & 1u)) >> 16;
    return (unsigned short)r;
}
static __device__ __forceinline__ float bflo(unsigned u) {
    return __uint_as_float(u << 16);
}
static __device__ __forceinline__ float bfhi(unsigned u) {
    return __uint_as_float(u & 0xffff0000u);
}

// ====== fused: wide cvt (blocks [0,CVT)) + hist (rest), sequential halves ======
__global__ __launch_bounds__(256) void lgcn_cvt_hist(
    const fx4* __restrict__ emb4, ui4* __restrict__ dst,
    const int* __restrict__ col, int* __restrict__ cnt)
{
    if (blockIdx.x < CVT_BLOCKS) {
        int i = blockIdx.x * 256 + threadIdx.x;       // one ui4 (=2 float4) /thread
        fx4 v0 = __builtin_nontemporal_load(&emb4[2 * i]);
        fx4 v1 = __builtin_nontemporal_load(&emb4[2 * i + 1]);
        ui4 o;
        o.x = (unsigned)f2bf(v0.x) | ((unsigned)f2bf(v0.y) << 16);
        o.y = (unsigned)f2bf(v0.z) | ((unsigned)f2bf(v0.w) << 16);
        o.z = (unsigned)f2bf(v1.x) | ((unsigned)f2bf(v1.y) << 16);
        o.w = (unsigned)f2bf(v1.z) | ((unsigned)f2bf(v1.w) << 16);
        dst[i] = o;                                   // cached 16B store
    } else {
        int t = (blockIdx.x - CVT_BLOCKS) * 256 + threadIdx.x;
        if (t >= NEDGE / 2) return;
        int2 c2 = reinterpret_cast<const int2*>(col)[t];
        if ((unsigned)c2.x < NNODES) atomicAdd(&cnt[c2.x], 1);
        if ((unsigned)c2.y < NNODES) atomicAdd(&cnt[c2.y], 1);
    }
}

// ======================= CSR scans =======================

__global__ __launch_bounds__(SCAN_BLK) void lgcn_scan1(
    const int* __restrict__ cnt, int* __restrict__ startv, int* __restrict__ bsum)
{
    __shared__ int sh[SCAN_BLK];
    int b = blockIdx.x;
    int base = b * SCAN_CHUNK;
    int tid = threadIdx.x;
    int v[SCAN_ITEMS];
    int local = 0;
    #pragma unroll
    for (int k = 0; k < SCAN_ITEMS; ++k) {
        int idx = base + tid * SCAN_ITEMS + k;
        v[k] = (idx < NNODES) ? cnt[idx] : 0;
        local += v[k];
    }
    sh[tid] = local;
    __syncthreads();
    for (int off = 1; off < SCAN_BLK; off <<= 1) {
        int x = (tid >= off) ? sh[tid - off] : 0;
        __syncthreads();
        sh[tid] += x;
        __syncthreads();
    }
    int run = (tid == 0) ? 0 : sh[tid - 1];
    if (tid == SCAN_BLK - 1) bsum[b] = sh[tid];
    #pragma unroll
    for (int k = 0; k < SCAN_ITEMS; ++k) {
        int idx = base + tid * SCAN_ITEMS + k;
        if (idx < NNODES) startv[idx] = run;
        run += v[k];
    }
}

__global__ __launch_bounds__(SCAN_BLK) void lgcn_scan2(int* __restrict__ bsum)
{
    __shared__ int sh[SCAN_BLK];
    int tid = threadIdx.x;
    sh[tid] = (tid < NB1) ? bsum[tid] : 0;
    __syncthreads();
    for (int off = 1; off < SCAN_BLK; off <<= 1) {
        int x = (tid >= off) ? sh[tid - off] : 0;
        __syncthreads();
        sh[tid] += x;
        __syncthreads();
    }
    if (tid < NB1) bsum[tid] = (tid == 0) ? 0 : sh[tid - 1];
}

__global__ __launch_bounds__(256) void lgcn_scan3(
    int* __restrict__ startv, int* __restrict__ cursor, const int* __restrict__ bsum)
{
    int i = blockIdx.x * blockDim.x + threadIdx.x;
    if (i < NNODES) {
        int s = startv[i] + bsum[i / SCAN_CHUNK];
        startv[i] = s;
        cursor[i] = s;
    }
    if (i == 0) startv[NNODES] = NEDGE;
}

// ============ fill: XCD-class col partition (blockIdx&7 == class) ============
__global__ __launch_bounds__(256) void lgcn_fill_part(
    const int* __restrict__ row, const int* __restrict__ col,
    const float* __restrict__ w, int* __restrict__ cursor,
    unsigned long long* __restrict__ pairs)
{
    const int cls = blockIdx.x & (FILL_CLASSES - 1);
    const int q   = blockIdx.x >> 3;
    const int lo  = cls * COLS_PER_CLS;
    const int hi  = lo + COLS_PER_CLS;
    const int2* col2 = reinterpret_cast<const int2*>(col);

    for (int t = q * 256 + threadIdx.x; t < NEDGE / 2; t += FILL_BPC * 256) {
        int2 c2 = col2[t];
        if (c2.x >= lo && c2.x < hi) {
            int e = 2 * t;
            int r = row[e]; float wt = w[e];
            if ((unsigned)r >= NNODES) { r = 0; wt = 0.f; }
            int p = atomicAdd(&cursor[c2.x], 1);
            pairs[p] = (unsigned long long)(unsigned)r
                     | ((unsigned long long)__float_as_uint(wt) << 32);
        }
        if (c2.y >= lo && c2.y < hi) {
            int e = 2 * t + 1;
            int r = row[e]; float wt = w[e];
            if ((unsigned)r >= NNODES) { r = 0; wt = 0.f; }
            int p = atomicAdd(&cursor[c2.y], 1);
            pairs[p] = (unsigned long long)(unsigned)r
                     | ((unsigned long long)__float_as_uint(wt) << 32);
        }
    }
}

// ======================= gather: 8 nodes/wave, 8 lanes/node =======================
// Unconditional clamped batch loads (r14-proven). Table writes CACHED so the
// next gather reads an L2/L3-hot table.
// MODE 0: E16 -> X1;  MODE 1: X1 -> X2;  MODE 2: X2+streams -> out fp32
template<int MODE>
__global__ __launch_bounds__(256, 4) void lgcn_gather(
    const unsigned short* __restrict__ src16, unsigned short* __restrict__ xout16,
    const float* __restrict__ emb, const unsigned short* __restrict__ x1,
    const unsigned short* __restrict__ x2, float* __restrict__ outp,
    const int2* __restrict__ pairs, const int* __restrict__ startv)
{
    int t = blockIdx.x * blockDim.x + threadIdx.x;
    int wid = t >> 6;               // wave id: 8 nodes/wave
    int lane = t & 63;
    int g = lane >> 3;              // node slot (0..7)
    int sub = lane & 7;             // dim octet (dims sub*8 .. sub*8+7)
    int n = wid * 8 + g;
    if (n >= NNODES) return;

    int s = startv[n];              // broadcast within 8-lane group
    int e = startv[n + 1];

    float a0=0.f,a1=0.f,a2=0.f,a3=0.f,a4=0.f,a5=0.f,a6=0.f,a7=0.f;

    for (int i = s; i < e; i += 8) {     // empty nodes skip entirely
        int2 pr[8];
        #pragma unroll
        for (int k = 0; k < 8; ++k) {
            int idx = i + k;
            idx = idx < e ? idx : e - 1;     // clamp; e>s here so e-1>=s
            pr[k] = pairs[idx];              // unconditional broadcast load
        }
        uint4 rv[8];
        #pragma unroll
        for (int k = 0; k < 8; ++k) {
            rv[k] = *reinterpret_cast<const uint4*>(
                &src16[(size_t)pr[k].x * DIMV + sub * 8]);   // unconditional
        }
        #pragma unroll
        for (int k = 0; k < 8; ++k) {
            float wk = (i + k < e) ? __int_as_float(pr[k].y) : 0.f;
            a0 = fmaf(wk, bflo(rv[k].x), a0);
            a1 = fmaf(wk, bfhi(rv[k].x), a1);
            a2 = fmaf(wk, bflo(rv[k].y), a2);
            a3 = fmaf(wk, bfhi(rv[k].y), a3);
            a4 = fmaf(wk, bflo(rv[k].z), a4);
            a5 = fmaf(wk, bfhi(rv[k].z), a5);
            a6 = fmaf(wk, bflo(rv[k].w), a6);
            a7 = fmaf(wk, bfhi(rv[k].w), a7);
        }
    }

    const size_t o = (size_t)n * DIMV + sub * 8;
    if (MODE == 2) {
        fx4 e0 = __builtin_nontemporal_load(reinterpret_cast<const fx4*>(&emb[o]));
        fx4 e1 = __builtin_nontemporal_load(reinterpret_cast<const fx4*>(&emb[o + 4]));
        uint4 u1 = *reinterpret_cast<const uint4*>(&x1[o]);      // cache-hot
        uint4 u2 = *reinterpret_cast<const uint4*>(&x2[o]);      // cache-hot
        fx4 r0, r1;
        r0.x = (e0.x + bflo(u1.x) + bflo(u2.x) + a0) * 0.25f;
        r0.y = (e0.y + bfhi(u1.x) + bfhi(u2.x) + a1) * 0.25f;
        r0.z = (e0.z + bflo(u1.y) + bflo(u2.y) + a2) * 0.25f;
        r0.w = (e0.w + bfhi(u1.y) + bfhi(u2.y) + a3) * 0.25f;
        r1.x = (e1.x + bflo(u1.z) + bflo(u2.z) + a4) * 0.25f;
        r1.y = (e1.y + bfhi(u1.z) + bfhi(u2.z) + a5) * 0.25f;
        r1.z = (e1.z + bflo(u1.w) + bflo(u2.w) + a6) * 0.25f;
        r1.w = (e1.w + bfhi(u1.w) + bfhi(u2.w) + a7) * 0.25f;
        __builtin_nontemporal_store(r0, reinterpret_cast<fx4*>(&outp[o]));
        __builtin_nontemporal_store(r1, reinterpret_cast<fx4*>(&outp[o + 4]));
    } else {
        unsigned long long lo =
              (unsigned long long)((unsigned)f2bf(a0) | ((unsigned)f2bf(a1) << 16))
            | ((unsigned long long)((unsigned)f2bf(a2) | ((unsigned)f2bf(a3) << 16)) << 32);
        unsigned long long hi =
              (unsigned long long)((unsigned)f2bf(a4) | ((unsigned)f2bf(a5) << 16))
            | ((unsigned long long)((unsigned)f2bf(a6) | ((unsigned)f2bf(a7) << 16)) << 32);
        // CACHED stores: this table is the next gather's random-read source
        reinterpret_cast<unsigned long long*>(&xout16[o])[0]    = lo;
        reinterpret_cast<unsigned long long*>(&xout16[o + 4])[0] = hi;
    }
}

// ======================= fallback: atomic scatter path (fp32) =======================

__global__ __launch_bounds__(256) void lgcn_init(
    const float4* __restrict__ emb, float4* __restrict__ acc,
    float4* __restrict__ A, float4* __restrict__ B)
{
    int i = blockIdx.x * blockDim.x + threadIdx.x;
    int stride = gridDim.x * blockDim.x;
    for (; i < NELEM4; i += stride) {
        float4 v = emb[i];
        acc[i] = v;
        A[i]   = v;
        B[i]   = make_float4(0.f, 0.f, 0.f, 0.f);
    }
}

__global__ __launch_bounds__(256) void lgcn_scatter(
    const float* __restrict__ xcur, float* __restrict__ xnext,
    const int* __restrict__ row, const int* __restrict__ col,
    const float* __restrict__ w)
{
    int t = blockIdx.x * blockDim.x + threadIdx.x;
    int e = t >> 4;
    if (e >= NEDGE) return;
    int d = (t & 15) << 2;
    int r = row[e];
    int c = col[e];
    if ((unsigned)r >= NNODES || (unsigned)c >= NNODES) return;
    float wt = w[e];
    const float4 v = *reinterpret_cast<const float4*>(xcur + (size_t)r * DIMV + d);
    float* dst = xnext + (size_t)c * DIMV + d;
    atomicAdd(dst + 0, wt * v.x);
    atomicAdd(dst + 1, wt * v.y);
    atomicAdd(dst + 2, wt * v.z);
    atomicAdd(dst + 3, wt * v.w);
}

__global__ __launch_bounds__(256) void lgcn_addzero(
    float4* __restrict__ acc, const float4* __restrict__ X, float4* __restrict__ Y)
{
    int i = blockIdx.x * blockDim.x + threadIdx.x;
    int stride = gridDim.x * blockDim.x;
    for (; i < NELEM4; i += stride) {
        float4 a = acc[i];
        float4 x = X[i];
        a.x += x.x; a.y += x.y; a.z += x.z; a.w += x.w;
        acc[i] = a;
        Y[i] = make_float4(0.f, 0.f, 0.f, 0.f);
    }
}

__global__ __launch_bounds__(256) void lgcn_final(
    float4* __restrict__ acc, const float4* __restrict__ X)
{
    int i = blockIdx.x * blockDim.x + threadIdx.x;
    int stride = gridDim.x * blockDim.x;
    for (; i < NELEM4; i += stride) {
        float4 a = acc[i];
        float4 x = X[i];
        a.x = (a.x + x.x) * 0.25f;
        a.y = (a.y + x.y) * 0.25f;
        a.z = (a.z + x.z) * 0.25f;
        a.w = (a.w + x.w) * 0.25f;
        acc[i] = a;
    }
}

// ======================= launch =======================

extern "C" void kernel_launch(void* const* d_in, const int* in_sizes, int n_in,
                              void* d_out, int out_size, void* d_ws, size_t ws_size,
                              hipStream_t stream) {
    const float* emb  = (const float*)d_in[0];   // [N, 64] fp32
    const int*   eidx = (const int*)d_in[1];     // [2, E] int32
    const float* ew   = (const float*)d_in[2];   // [E] fp32
    float* acc = (float*)d_out;                  // [N, 64]

    const int* row = eidx;
    const int* col = eidx + NEDGE;

    // workspace: E16, X1, X2 (bf16, 64 MB each) + CSR arrays
    unsigned short* E16 = (unsigned short*)d_ws;         // NELEM*2
    unsigned short* X1  = E16 + NELEM;                   // NELEM*2
    unsigned short* X2  = X1 + NELEM;                    // NELEM*2
    int2*  pairs  = (int2*)(X2 + NELEM);                 // 10e6 B (8-aligned)
    int*   startv = (int*)(pairs + NEDGE);               // (N+1)*4
    int*   cursor = startv + (NNODES + 1);               // N*4
    int*   bsum   = cursor + NNODES;                     // NB1*4
    const size_t needed = (size_t)3 * NELEM * 2 + (size_t)NEDGE * 8
                        + ((size_t)NNODES + 1) * 4 + (size_t)NNODES * 4 + (size_t)NB1 * 4;

    const int NODE_BLOCKS = (NNODES + 255) / 256;
    const int GW_BLOCKS   = (NNODES * 8 + 255) / 256;    // 8 nodes/wave

    if (ws_size >= needed) {
        // ---- fused bf16 table + CSR counts ----
        hipMemsetAsync(cursor, 0, (size_t)NNODES * 4, stream);
        lgcn_cvt_hist<<<CVT_BLOCKS + EDGE2_BLOCKS, 256, 0, stream>>>(
            (const fx4*)emb, (ui4*)E16, col, cursor);

        // ---- scans + partitioned fill ----
        lgcn_scan1<<<NB1, SCAN_BLK, 0, stream>>>(cursor, startv, bsum);
        lgcn_scan2<<<1, SCAN_BLK, 0, stream>>>(bsum);
        lgcn_scan3<<<NODE_BLOCKS, 256, 0, stream>>>(startv, cursor, bsum);
        lgcn_fill_part<<<FILL_CLASSES * FILL_BPC, 256, 0, stream>>>(
            row, col, ew, cursor, (unsigned long long*)pairs);

        // ---- layers ----
        lgcn_gather<0><<<GW_BLOCKS, 256, 0, stream>>>(
            E16, X1, nullptr, nullptr, nullptr, nullptr, pairs, startv);
        lgcn_gather<1><<<GW_BLOCKS, 256, 0, stream>>>(
            X1, X2, nullptr, nullptr, nullptr, nullptr, pairs, startv);
        lgcn_gather<2><<<GW_BLOCKS, 256, 0, stream>>>(
            X2, nullptr, emb, X1, X2, acc, pairs, startv);
    } else {
        // ---- fallback: proven fp32 atomic-scatter path ----
        float* A = (float*)d_ws;
        float* B = A + NELEM;
        const int SC_BLOCKS = (NEDGE * 16 + 255) / 256;
        lgcn_init<<<2048, 256, 0, stream>>>(
            (const float4*)emb, (float4*)acc, (float4*)A, (float4*)B);
        lgcn_scatter<<<SC_BLOCKS, 256, 0, stream>>>(A, B, row, col, ew);
        lgcn_addzero<<<2048, 256, 0, stream>>>((float4*)acc, (const float4*)B, (float4*)A);
        lgcn_scatter<<<SC_BLOCKS, 256, 0, stream>>>(B, A, row, col, ew);
        lgcn_addzero<<<2048, 256, 0, stream>>>((float4*)acc, (const float4*)A, (float4*)B);
        lgcn_scatter<<<SC_BLOCKS, 256, 0, stream>>>(A, B, row, col, ew);
        lgcn_final<<<2048, 256, 0, stream>>>((float4*)acc, (const float4*)B);
    }
}